// Round 6
// baseline (144.481 us; speedup 1.0000x reference)
//
#include <hip/hip_runtime.h>
#include <math.h>

// VQ-VAE VectorQuantizer forward (MFMA bf16-split formulation), round N+6.
// R5 post-mortem: zero-barrier wave-private pipeline works (63us) but each
// wave read ALL 512KB of codes -> 1GB device L2 traffic (~30us floor).
// This round: K-SPLIT ACROSS WAVES — wave w owns codes [w*256,(w+1)*256)
// (8 mini-chunks) and computes them against ALL 8 point-tiles of the block.
//   - staging traffic 8x down (128MB device, ~4us L2); K-loop still ZERO
//     barriers (sbuf region, ecb slice, topw slice all wave-private).
//   - packed id = local code kloc (8 bits exactly); k = wv*256 + id.
//   - post-loop in-wave quad top-2 merge via 2x shfl_xor; per-wave results
//     stored in the wave's own dead sbuf region -> merge phase keeps the
//     proven 4-source x top-2 shape; gate/refine/phase4 verbatim R3.
//   - staging image re-laid fragment-linear (no swizzle needed: reads are
//     canonical lane-linear ds_read_b128, conflict-free).
// Cost: Bh/Bl[8][2] = 128 VGPR (est total ~200 < 256 cliff), 4x x-split VALU.

typedef __attribute__((ext_vector_type(8))) short short8v;
typedef __attribute__((ext_vector_type(4))) float float4v;
typedef unsigned short u16;
typedef unsigned int u32;

constexpr int D = 64;
constexpr int K = 1024;
constexpr int NPTS = 65536;
constexpr long QOFF = (long)NPTS * D;  // 4194304
constexpr float BIAS = 24.0f;
constexpr float GATE = 5e-3f;  // 2*(split 5e-4 + pack 1e-3) + ref err 2e-4 + margin

// ws layout (16B-aligned sections):
constexpr size_t OFF_LOSS = 0;                               // double
constexpr size_t OFF_CNT  = 256;                             // int[1024]
constexpr size_t OFF_EC   = OFF_CNT + 4096;                  // float[1024] ref-order norms
constexpr size_t OFF_ECB  = OFF_EC + 4096;                   // float[1024] norms + BIAS
constexpr size_t OFF_ET   = OFF_ECB + 4096;                  // float[1024*64] E transposed [k][d]
constexpr size_t OFF_STG  = OFF_ET + (size_t)K * D * 4;      // 256KB fragment-linear staging image

__device__ __forceinline__ float med3(float a, float b, float c) {
  return __builtin_amdgcn_fmed3f(a, b, c);
}
__device__ __forceinline__ u16 bf16rtn(float x) {
  u32 u = __float_as_uint(x);
  return (u16)((u + 0x7fffu + ((u >> 16) & 1u)) >> 16);
}
__device__ __forceinline__ float bf2f(u16 h) {
  return __uint_as_float(((u32)h) << 16);
}
// async global->LDS, 16B per lane; dest must be wave-uniform base + lane*16.
__device__ __forceinline__ void gl_lds16(const void* g, void* l) {
  __builtin_amdgcn_global_load_lds(
      (const __attribute__((address_space(1))) u32*)g,
      (__attribute__((address_space(3))) u32*)l, 16, 0, 0);
}

// ---------------------------------------------------------------------------
// Prep, grid 36 x 256:
//   blocks 0..31: Et rows + fragment-linear -2E bf16 hi/lo staging image.
//   blocks 32..35: ref-order ||e_k||^2, eCb, counts/loss zeroing.
// Fragment-linear image: 64 tiles of 16 codes; tile t = k>>4 at byte t*4096;
//   frag f in {0:hi-s0, 1:hi-s1, 2:lo-s0, 3:lo-s1} at f*1024;
//   16B unit for (code k, d-octet q of s-half) at lane (q*16 + (k&15)) * 16.
// A wave's ds_read of frag f for tile t is lane-linear (conflict-free) and
// gl_lds staging of a whole 8KB chunk (2 tiles) is a contiguous copy.
__global__ __launch_bounds__(256) void vq_prep(const float* __restrict__ E,
                                               float* __restrict__ eC,
                                               float* __restrict__ eCb,
                                               float* __restrict__ Et,
                                               unsigned char* __restrict__ stg,
                                               double* __restrict__ lossSum,
                                               int* __restrict__ counts) {
  const int b = blockIdx.x;
  const int tid = threadIdx.x;
  if (b < 32) {
    int gid = b * 256 + tid;
    int k = gid & 1023;        // block covers 256 consecutive k -> coalesced
    int g = gid >> 10;         // d-group 0..7, d = g*8 + j
    float v[8];
#pragma unroll
    for (int j = 0; j < 8; ++j) v[j] = E[(g * 8 + j) * K + k];
    *(float4*)&Et[(size_t)k * 64 + g * 8] = make_float4(v[0], v[1], v[2], v[3]);
    *(float4*)&Et[(size_t)k * 64 + g * 8 + 4] = make_float4(v[4], v[5], v[6], v[7]);
    short8v hv, lv;
#pragma unroll
    for (int j = 0; j < 8; ++j) {
      float m2 = -2.0f * v[j];  // exact
      u16 h = bf16rtn(m2);
      hv[j] = (short)h;
      lv[j] = (short)bf16rtn(m2 - bf2f(h));
    }
    int s = g >> 2, q = g & 3;  // d = s*32 + q*8 + j
    size_t tb = (size_t)(k >> 4) * 4096;
    int lanoff = (q * 16 + (k & 15)) * 16;
    *(short8v*)&stg[tb + (size_t)s * 1024 + lanoff] = hv;        // hi frag
    *(short8v*)&stg[tb + (size_t)(2 + s) * 1024 + lanoff] = lv;  // lo frag
  } else {
    int k = (b - 32) * 256 + tid;  // 0..1023
    float c = __fmul_rn(E[k], E[k]);
#pragma unroll
    for (int d = 1; d < D; ++d) {
      float vv = E[d * K + k];
      c = __fadd_rn(c, __fmul_rn(vv, vv));
    }
    eC[k] = c;
    eCb[k] = c + BIAS;
    counts[k] = 0;
    if (k == 0) *lossSum = 0.0;
  }
}

// ---------------------------------------------------------------------------
__global__ __launch_bounds__(256) void vq_main(const float* __restrict__ x,
                                               const unsigned char* __restrict__ stg,
                                               const float* __restrict__ eC,
                                               const float* __restrict__ eCb,
                                               const float* __restrict__ Etg,
                                               float* __restrict__ out,
                                               double* __restrict__ lossSum,
                                               int* __restrict__ counts) {
  // Wave-private staging: sbuf[wave][buf] 8KB = 64KB; + ecb 4KB + bkbuf
  // ~68.6KB => 2 blocks/CU. topw (1KB/wave) aliases the wave's dead sbuf.
  __shared__ __align__(16) unsigned char sbuf[4][2][8192];
  __shared__ __align__(16) float ecb[1024];
  __shared__ int bkbuf[128];

  const int tid = threadIdx.x;
  const int w = tid >> 6;        // wave id: owns codes [w*256, (w+1)*256)
  const int lane = tid & 63;
  const int col = lane & 15;     // A: code row; B/C: point col
  const int quad = lane >> 4;    // k-group (A/B), row-group (C)
  const int blockBase = blockIdx.x * 128;
  const float INF = __builtin_inff();

  // ---- phase 0: biased norms -> LDS. Wave w's tids write exactly
  // ecb[w*256,(w+1)*256) = the slice wave w reads: wave-private, no barrier.
  *(float4*)&ecb[tid * 4] = *(const float4*)&eCb[tid * 4];

  // ---- phase 1: load + split ALL 8 point-tiles into B-fragments ----
  short8v Bh[8][2], Bl[8][2];
#pragma unroll
  for (int pt = 0; pt < 8; ++pt) {
    const float* xp = x + (size_t)(blockBase + pt * 16 + col) * 64;
#pragma unroll
    for (int s = 0; s < 2; ++s) {
      const float4* src = (const float4*)(xp + s * 32 + quad * 8);
      float4 a = src[0], b = src[1];
      float xs[8] = {a.x, a.y, a.z, a.w, b.x, b.y, b.z, b.w};
      short8v hf, lf;
#pragma unroll
      for (int j = 0; j < 8; ++j) {
        u16 h = bf16rtn(xs[j]);
        hf[j] = (short)h;
        lf[j] = (short)bf16rtn(xs[j] - bf2f(h));
      }
      Bh[pt][s] = hf;
      Bl[pt][s] = lf;
    }
  }

  // ---- prologue: stage this wave's mini-chunks 0,1 (gl_lds AFTER the split
  // so x-load auto-waits never drain the staging queue) ----
  {
    const unsigned char* s0 = stg + (size_t)(w * 8) * 8192 + (size_t)lane * 16;
#pragma unroll
    for (int i = 0; i < 8; ++i)
      gl_lds16(s0 + i * 1024, &sbuf[w][0][i * 1024 + lane * 16]);
#pragma unroll
    for (int i = 0; i < 8; ++i)
      gl_lds16(s0 + 8192 + i * 1024, &sbuf[w][1][i * 1024 + lane * 16]);
  }

  // running top-2 of packed biased distances, per point-tile
  float b1[8] = {INF, INF, INF, INF, INF, INF, INF, INF};
  float b2[8] = {INF, INF, INF, INF, INF, INF, INF, INF};

  // ---- phase 2: K loop, 8 wave-private mini-chunks x 8 point-tiles ----
  // Zero barriers; double-buffer paced by counted vmcnt (issue ch+2, wait
  // ch via vmcnt(8): 8 newer loads = chunk ch+1 stay in flight).
#pragma unroll 1
  for (int ch = 0; ch < 8; ++ch) {
    const unsigned char* bufB = sbuf[w][ch & 1];
    if (ch < 7) {
      asm volatile("s_waitcnt vmcnt(8)" ::: "memory");
    } else {
      asm volatile("s_waitcnt vmcnt(0)" ::: "memory");
    }
#pragma unroll
    for (int ct2 = 0; ct2 < 2; ++ct2) {  // 2 code-tiles of 16
      const unsigned char* fb = bufB + ct2 * 4096 + lane * 16;  // lane-linear
      short8v Ah0 = *(const short8v*)(fb);
      short8v Ah1 = *(const short8v*)(fb + 1024);
      short8v Al0 = *(const short8v*)(fb + 2048);
      short8v Al1 = *(const short8v*)(fb + 3072);
      float4v Ci = *(const float4v*)&ecb[w * 256 + ch * 32 + ct2 * 16 + quad * 4];
      const int idb = ch * 32 + ct2 * 16 + quad * 4;  // local code base
#pragma unroll
      for (int pt = 0; pt < 8; ++pt) {
        // split accumulators: two independent 3-deep MFMA chains per pt
        float4v Ca = Ci;
        float4v Cb = {0.f, 0.f, 0.f, 0.f};
        Ca = __builtin_amdgcn_mfma_f32_16x16x32_bf16(Ah0, Bh[pt][0], Ca, 0, 0, 0);
        Cb = __builtin_amdgcn_mfma_f32_16x16x32_bf16(Ah1, Bh[pt][1], Cb, 0, 0, 0);
        Ca = __builtin_amdgcn_mfma_f32_16x16x32_bf16(Al0, Bh[pt][0], Ca, 0, 0, 0);
        Cb = __builtin_amdgcn_mfma_f32_16x16x32_bf16(Al1, Bh[pt][1], Cb, 0, 0, 0);
        Ca = __builtin_amdgcn_mfma_f32_16x16x32_bf16(Ah0, Bl[pt][0], Ca, 0, 0, 0);
        Cb = __builtin_amdgcn_mfma_f32_16x16x32_bf16(Ah1, Bl[pt][1], Cb, 0, 0, 0);
#pragma unroll
        for (int r = 0; r < 4; ++r) {
          float dv = Ca[r] + Cb[r];
          // pack local code id (= idb + r, 8 bits) into low mantissa bits;
          // id == k - w*256, ascending id == ascending k (tie -> lower k).
          u32 u = (__float_as_uint(dv) & 0xffffff00u) | (u32)(idb + r);
          float v = __uint_as_float(u);
          float pb = b1[pt];
          b1[pt] = fminf(pb, v);
          b2[pt] = med3(pb, b2[pt], v);
        }
      }
    }
    // my ds_reads of bufB delivered (wave-local), then overwrite with ch+2.
    asm volatile("s_waitcnt lgkmcnt(0)" ::: "memory");
    if (ch < 6) {
      const unsigned char* s2 =
          stg + (size_t)(w * 8 + ch + 2) * 8192 + (size_t)lane * 16;
#pragma unroll
      for (int i = 0; i < 8; ++i)
        gl_lds16(s2 + i * 1024, &sbuf[w][ch & 1][i * 1024 + lane * 16]);
    }
  }

  // ---- phase 3a: in-wave quad top-2 merge (shfl butterfly over lanes
  // ^16, ^32); store per-wave top-2 into the wave's own dead sbuf region ----
  float* topw = (float*)&sbuf[w][0][0];
#pragma unroll
  for (int pt = 0; pt < 8; ++pt) {
    float v1 = b1[pt], v2 = b2[pt];
#pragma unroll
    for (int off = 16; off <= 32; off <<= 1) {
      float r1 = __shfl_xor(v1, off, 64);
      float r2 = __shfl_xor(v2, off, 64);
      float hi = fmaxf(v1, r1);
      v1 = fminf(v1, r1);                 // merged min
      v2 = fminf(hi, fminf(v2, r2));      // merged 2nd
    }
    if (lane < 16) {
      topw[pt * 32 + col * 2] = v1;
      topw[pt * 32 + col * 2 + 1] = v2;
    }
  }
  __syncthreads();

  // ---- phase 3b: merge 4 wave-sources per point, gate + exact refine ----
  if (tid < 128) {  // one thread per point; tid = pt*16 + col
    const int mpt = tid >> 4, mcol = tid & 15;
    float cv[8];
    int cq[8];
    float mv0 = INF, mv1 = INF;
    int q0 = 0;
#pragma unroll
    for (int wv = 0; wv < 4; ++wv) {
      const float* tw = (const float*)&sbuf[wv][0][0];
#pragma unroll
      for (int j = 0; j < 2; ++j) {
        float v = tw[mpt * 32 + mcol * 2 + j];
        cv[wv * 2 + j] = v;
        cq[wv * 2 + j] = wv;
        if (v < mv0) { mv1 = mv0; mv0 = v; q0 = wv; }
        else if (v < mv1) { mv1 = v; }
      }
    }
    u32 lb = __float_as_uint(mv0) & 255u;
    int bestk = q0 * 256 + (int)lb;  // k = wave*256 + local id

    if (mv1 - mv0 < GATE) {
      // ----- exact emulation of the np reference's fp32 arithmetic -----
      const float* f = x + (size_t)(blockBase + tid) * 64;
      float r8[8];
#pragma unroll
      for (int j = 0; j < 8; ++j) { float fv = f[j]; r8[j] = __fmul_rn(fv, fv); }
#pragma unroll
      for (int i = 8; i < D; i += 8)
#pragma unroll
        for (int j = 0; j < 8; ++j) {
          float fv = f[i + j];
          r8[j] = __fadd_rn(r8[j], __fmul_rn(fv, fv));
        }
      float A = __fadd_rn(__fadd_rn(__fadd_rn(r8[0], r8[1]), __fadd_rn(r8[2], r8[3])),
                          __fadd_rn(__fadd_rn(r8[4], r8[5]), __fadd_rn(r8[6], r8[7])));
      float bd = INF;
      int bkk = K;
#pragma unroll
      for (int c = 0; c < 8; ++c) {
        int k = cq[c] * 256 + (int)(__float_as_uint(cv[c]) & 255u);
        // Et row is d-ascending -> identical fp32 fma sequence, contiguous loads
        const float* er = Etg + (size_t)k * 64;
        float m = 0.f;
#pragma unroll
        for (int d = 0; d < D; ++d) m = __fmaf_rn(f[d], er[d], m);
        float dist = __fadd_rn(__fsub_rn(A, __fmul_rn(2.f, m)), eC[k]);
        bool better = (dist < bd) || (dist == bd && k < bkk);
        bd = better ? dist : bd;
        bkk = better ? k : bkk;
      }
      bestk = bkk;
    }

    bkbuf[tid] = bestk;
    out[QOFF + 2 + blockBase + tid] = (float)bestk;  // index (exact as float)
    atomicAdd(&counts[bestk], 1);
  }
  __syncthreads();

  // ---- phase 4: quantized write (gather from Et, coalesced) + loss ----
  const int pp = tid >> 1, half = tid & 1;
  const int bk = bkbuf[pp];
  const float4* et = (const float4*)(Etg + (size_t)bk * 64 + half * 32);
  const float4* xr = (const float4*)(x + (size_t)(blockBase + pp) * 64 + half * 32);
  float4* ov = (float4*)(out + (size_t)(blockBase + pp) * 64 + half * 32);
  float errs = 0.f;
#pragma unroll
  for (int i = 0; i < 8; ++i) {
    float4 qv = et[i];
    float4 xv = xr[i];
    float dx;
    dx = qv.x - xv.x; errs = fmaf(dx, dx, errs);
    dx = qv.y - xv.y; errs = fmaf(dx, dx, errs);
    dx = qv.z - xv.z; errs = fmaf(dx, dx, errs);
    dx = qv.w - xv.w; errs = fmaf(dx, dx, errs);
    ov[i] = qv;
  }
  double de = (double)errs;
#pragma unroll
  for (int off = 32; off > 0; off >>= 1) de += __shfl_down(de, off, 64);
  if (lane == 0) atomicAdd(lossSum, de);
}

__global__ __launch_bounds__(256) void vq_finalize(const double* __restrict__ lossSum,
                                                   const int* __restrict__ counts,
                                                   float* __restrict__ out) {
  __shared__ double sh[256];
  double ent = 0.0;
  for (int k = threadIdx.x; k < K; k += 256) {
    double pp = (double)counts[k] / (double)NPTS;
    ent += pp * log(pp + 1e-10);
  }
  sh[threadIdx.x] = ent;
  __syncthreads();
  for (int s = 128; s > 0; s >>= 1) {
    if (threadIdx.x < s) sh[threadIdx.x] += sh[threadIdx.x + s];
    __syncthreads();
  }
  if (threadIdx.x == 0) {
    // loss = q_latent + 0.25 * e_latent = 1.25 * mean((q - x)^2)
    out[QOFF + 0] = (float)(1.25 * (*lossSum) / (double)((long)NPTS * D));
    out[QOFF + 1] = (float)exp(-sh[0]);  // perplexity
  }
}

extern "C" void kernel_launch(void* const* d_in, const int* in_sizes, int n_in,
                              void* d_out, int out_size, void* d_ws, size_t ws_size,
                              hipStream_t stream) {
  const float* x = (const float*)d_in[0];
  const float* E = (const float*)d_in[1];
  float* out = (float*)d_out;

  char* ws = (char*)d_ws;
  double* lossSum = (double*)(ws + OFF_LOSS);
  int* counts = (int*)(ws + OFF_CNT);
  float* eC = (float*)(ws + OFF_EC);
  float* eCb = (float*)(ws + OFF_ECB);
  float* Etg = (float*)(ws + OFF_ET);
  unsigned char* stgb = (unsigned char*)(ws + OFF_STG);

  // prep zeroes lossSum/counts itself (ws is poisoned before every timed
  // launch); no memset dispatch needed.
  vq_prep<<<36, 256, 0, stream>>>(E, eC, eCb, Etg, stgb, lossSum, counts);
  vq_main<<<NPTS / 128, 256, 0, stream>>>(x, stgb, eC, eCb, Etg, out,
                                          lossSum, counts);
  vq_finalize<<<1, 256, 0, stream>>>(lossSum, counts, out);
}

// Round 7
// 135.688 us; speedup vs baseline: 1.0648x; 1.0648x over previous
//
#include <hip/hip_runtime.h>
#include <math.h>

// VQ-VAE VectorQuantizer forward (MFMA bf16-split formulation), round N+7.
// R6 post-mortem: K-split regressed (VGPR 100->208 pressure) BUT proved the
// fragment-linear staging layout kills the 2.1M K-loop bank conflicts.
// This round: verbatim R5 main structure (63us, point-split, zero-barrier
// wave-private K-loop) + two disjoint grafts:
//   1. fragment-linear stg image (R6 prep) -> lane-linear conflict-free
//      ds_read_b128 A-fragments (no XOR swizzle).            [tripwire: LDS_BANK_CONFLICT]
//   2. ticket-fused finalize WITHOUT __threadfence (R2's poison was the
//      fence's L2 writeback, WRITE +12MB). __syncthreads drains vmcnt(0)
//      => device-scope atomics performed before ticket; last block reads
//      counts/lossSum via agent-scope atomic loads only.     [tripwire: WRITE_SIZE]
// Dispatches 3 -> 2 (finalize+gap was ~26us of the 66us non-main time).

typedef __attribute__((ext_vector_type(8))) short short8v;
typedef __attribute__((ext_vector_type(4))) float float4v;
typedef unsigned short u16;
typedef unsigned int u32;

constexpr int D = 64;
constexpr int K = 1024;
constexpr int NPTS = 65536;
constexpr long QOFF = (long)NPTS * D;  // 4194304
constexpr float BIAS = 24.0f;
constexpr float GATE = 5e-3f;  // 2*(split 5e-4 + pack 1e-3) + ref err 2e-4 + margin

// ws layout (16B-aligned sections):
constexpr size_t OFF_LOSS = 0;                               // double
constexpr size_t OFF_DONE = 16;                              // int ticket
constexpr size_t OFF_CNT  = 256;                             // int[1024]
constexpr size_t OFF_EC   = OFF_CNT + 4096;                  // float[1024] ref-order norms
constexpr size_t OFF_ECB  = OFF_EC + 4096;                   // float[1024] norms + BIAS
constexpr size_t OFF_ET   = OFF_ECB + 4096;                  // float[1024*64] E transposed [k][d]
constexpr size_t OFF_STG  = OFF_ET + (size_t)K * D * 4;      // 256KB fragment-linear staging image

__device__ __forceinline__ float med3(float a, float b, float c) {
  return __builtin_amdgcn_fmed3f(a, b, c);
}
__device__ __forceinline__ u16 bf16rtn(float x) {
  u32 u = __float_as_uint(x);
  return (u16)((u + 0x7fffu + ((u >> 16) & 1u)) >> 16);
}
__device__ __forceinline__ float bf2f(u16 h) {
  return __uint_as_float(((u32)h) << 16);
}
// async global->LDS, 16B per lane; dest must be wave-uniform base + lane*16.
__device__ __forceinline__ void gl_lds16(const void* g, void* l) {
  __builtin_amdgcn_global_load_lds(
      (const __attribute__((address_space(1))) u32*)g,
      (__attribute__((address_space(3))) u32*)l, 16, 0, 0);
}

// ---------------------------------------------------------------------------
// Prep, grid 36 x 256 (R6's fragment-linear image — proven correct):
//   blocks 0..31: Et rows + fragment-linear -2E bf16 hi/lo staging image.
//   blocks 32..35: ref-order ||e_k||^2, eCb, counts/loss/ticket zeroing.
// Fragment-linear image: 64 tiles of 16 codes; tile t = k>>4 at byte t*4096;
//   frag f in {0:hi-s0, 1:hi-s1, 2:lo-s0, 3:lo-s1} at f*1024;
//   16B unit for (code k, d-octet q of s-half) at lane (q*16 + (k&15)) * 16.
// Wave ds_read of a frag is lane-linear (conflict-free); staging a whole 8KB
// chunk (2 tiles = 32 codes) is a contiguous 16B-granular copy.
__global__ __launch_bounds__(256) void vq_prep(const float* __restrict__ E,
                                               float* __restrict__ eC,
                                               float* __restrict__ eCb,
                                               float* __restrict__ Et,
                                               unsigned char* __restrict__ stg,
                                               double* __restrict__ lossSum,
                                               int* __restrict__ counts,
                                               int* __restrict__ done) {
  const int b = blockIdx.x;
  const int tid = threadIdx.x;
  if (b < 32) {
    int gid = b * 256 + tid;
    int k = gid & 1023;        // block covers 256 consecutive k -> coalesced
    int g = gid >> 10;         // d-group 0..7, d = g*8 + j
    float v[8];
#pragma unroll
    for (int j = 0; j < 8; ++j) v[j] = E[(g * 8 + j) * K + k];
    *(float4*)&Et[(size_t)k * 64 + g * 8] = make_float4(v[0], v[1], v[2], v[3]);
    *(float4*)&Et[(size_t)k * 64 + g * 8 + 4] = make_float4(v[4], v[5], v[6], v[7]);
    short8v hv, lv;
#pragma unroll
    for (int j = 0; j < 8; ++j) {
      float m2 = -2.0f * v[j];  // exact
      u16 h = bf16rtn(m2);
      hv[j] = (short)h;
      lv[j] = (short)bf16rtn(m2 - bf2f(h));
    }
    int s = g >> 2, q = g & 3;  // d = s*32 + q*8 + j
    size_t tb = (size_t)(k >> 4) * 4096;
    int lanoff = (q * 16 + (k & 15)) * 16;
    *(short8v*)&stg[tb + (size_t)s * 1024 + lanoff] = hv;        // hi frag
    *(short8v*)&stg[tb + (size_t)(2 + s) * 1024 + lanoff] = lv;  // lo frag
  } else {
    int k = (b - 32) * 256 + tid;  // 0..1023
    float c = __fmul_rn(E[k], E[k]);
#pragma unroll
    for (int d = 1; d < D; ++d) {
      float vv = E[d * K + k];
      c = __fadd_rn(c, __fmul_rn(vv, vv));
    }
    eC[k] = c;
    eCb[k] = c + BIAS;
    counts[k] = 0;
    if (k == 0) { *lossSum = 0.0; *done = 0; }
  }
}

// ---------------------------------------------------------------------------
// R5 vq_main (measured 63us) + fragment-linear ds_reads + ticket finalize.
__global__ __launch_bounds__(256) void vq_main(const float* __restrict__ x,
                                               const unsigned char* __restrict__ stg,
                                               const float* __restrict__ eC,
                                               const float* __restrict__ eCb,
                                               const float* __restrict__ Etg,
                                               float* __restrict__ out,
                                               double* __restrict__ lossSum,
                                               int* __restrict__ counts,
                                               int* __restrict__ done) {
  // Wave-private staging: sbuf[wave][buf] 8KB each = 64KB; + ecb 4KB +
  // topbuf 4KB + bkbuf -> ~72.7KB => 2 blocks/CU.
  __shared__ __align__(16) unsigned char sbuf[4][2][8192];
  __shared__ __align__(16) float ecb[1024];
  __shared__ __align__(16) float topbuf[256 * 4];
  __shared__ int bkbuf[128];
  __shared__ int lastFlag;

  const int tid = threadIdx.x;
  const int w = tid >> 6;        // wave id: owns point-tiles 2w, 2w+1
  const int lane = tid & 63;
  const int col = lane & 15;     // A: code row; B/C: point col
  const int quad = lane >> 4;    // k-group (A/B), row-group (C)
  const int blockBase = blockIdx.x * 128;
  const float INF = __builtin_inff();

  // ---- phase 0: stage all biased norms once (plain LDS copy) ----
  *(float4*)&ecb[tid * 4] = *(const float4*)&eCb[tid * 4];

  // ---- phase 1: load + split x into B-fragments (register-resident) ----
  short8v Bh[2][2], Bl[2][2];
#pragma unroll
  for (int pt = 0; pt < 2; ++pt) {
    const float* xp = x + (size_t)(blockBase + w * 32 + pt * 16 + col) * 64;
#pragma unroll
    for (int s = 0; s < 2; ++s) {
      const float4* src = (const float4*)(xp + s * 32 + quad * 8);
      float4 a = src[0], b = src[1];
      float xs[8] = {a.x, a.y, a.z, a.w, b.x, b.y, b.z, b.w};
      short8v hf, lf;
#pragma unroll
      for (int j = 0; j < 8; ++j) {
        u16 h = bf16rtn(xs[j]);
        hf[j] = (short)h;
        lf[j] = (short)bf16rtn(xs[j] - bf2f(h));
      }
      Bh[pt][s] = hf;
      Bl[pt][s] = lf;
    }
  }

  // ---- prologue: this wave stages mini-chunks 0 and 1 into its own bufs ----
  {
    const unsigned char* s0 = stg + (size_t)lane * 16;
#pragma unroll
    for (int i = 0; i < 8; ++i)
      gl_lds16(s0 + i * 1024, &sbuf[w][0][i * 1024 + lane * 16]);
#pragma unroll
    for (int i = 0; i < 8; ++i)
      gl_lds16(s0 + 8192 + i * 1024, &sbuf[w][1][i * 1024 + lane * 16]);
  }
  // ONE barrier: ecb ds_writes visible to all waves. No vmcnt drain — the
  // 16 staged loads stay in flight (wave-private, paced by vmcnt below).
  asm volatile("s_waitcnt lgkmcnt(0)" ::: "memory");
  __builtin_amdgcn_s_barrier();
  __builtin_amdgcn_sched_barrier(0);
  asm volatile("" ::: "memory");

  // running top-2 of packed biased distances, per point-tile
  float b1[2] = {INF, INF}, b2[2] = {INF, INF};

  // ---- phase 2: K loop, 32 wave-private mini-chunks of 32 codes ----
  // Zero barriers: each wave reads only LDS it staged itself; double-buffer
  // paced by counted vmcnt (issue ch+2, wait ch via vmcnt(8)).
#pragma unroll 1
  for (int ch = 0; ch < 32; ++ch) {
    const unsigned char* bufB = sbuf[w][ch & 1];
    if (ch < 31) {
      asm volatile("s_waitcnt vmcnt(8)" ::: "memory");   // ch landed; ch+1 may fly
    } else {
      asm volatile("s_waitcnt vmcnt(0)" ::: "memory");   // last chunk landed
    }
#pragma unroll
    for (int ct2 = 0; ct2 < 2; ++ct2) {  // 2 code-tiles of 16
      // fragment-linear: lane-linear 16B units, conflict-free ds_read_b128
      const unsigned char* fb = bufB + ct2 * 4096 + lane * 16;
      short8v Ah0 = *(const short8v*)(fb);
      short8v Ah1 = *(const short8v*)(fb + 1024);
      short8v Al0 = *(const short8v*)(fb + 2048);
      short8v Al1 = *(const short8v*)(fb + 3072);
      float4v Ci = *(const float4v*)&ecb[ch * 32 + ct2 * 16 + quad * 4];
#pragma unroll
      for (int pt = 0; pt < 2; ++pt) {
        // split accumulators: two independent 3-deep MFMA chains per pt
        float4v Ca = Ci;
        float4v Cb = {0.f, 0.f, 0.f, 0.f};
        Ca = __builtin_amdgcn_mfma_f32_16x16x32_bf16(Ah0, Bh[pt][0], Ca, 0, 0, 0);
        Cb = __builtin_amdgcn_mfma_f32_16x16x32_bf16(Ah1, Bh[pt][1], Cb, 0, 0, 0);
        Ca = __builtin_amdgcn_mfma_f32_16x16x32_bf16(Al0, Bh[pt][0], Ca, 0, 0, 0);
        Cb = __builtin_amdgcn_mfma_f32_16x16x32_bf16(Al1, Bh[pt][1], Cb, 0, 0, 0);
        Ca = __builtin_amdgcn_mfma_f32_16x16x32_bf16(Ah0, Bl[pt][0], Ca, 0, 0, 0);
        Cb = __builtin_amdgcn_mfma_f32_16x16x32_bf16(Ah1, Bl[pt][1], Cb, 0, 0, 0);
#pragma unroll
        for (int r = 0; r < 4; ++r) {
          float dv = Ca[r] + Cb[r];
          // pack local id (ch:5b | ct2:1b | r:2b) into low 8 mantissa bits;
          // (ch,ct2,r) lexicographic == ascending k for fixed quad => ties
          // still resolve toward lower k.
          u32 u = (__float_as_uint(dv) & 0xffffff00u) |
                  (u32)(ch * 8 + ct2 * 4 + r);
          float v = __uint_as_float(u);
          float pb = b1[pt];
          b1[pt] = fminf(pb, v);
          b2[pt] = med3(pb, b2[pt], v);
        }
      }
    }
    // my ds_reads of bufB delivered (wave-local), then overwrite with ch+2.
    asm volatile("s_waitcnt lgkmcnt(0)" ::: "memory");
    if (ch < 30) {
      const unsigned char* s2 = stg + (size_t)(ch + 2) * 8192 + (size_t)lane * 16;
#pragma unroll
      for (int i = 0; i < 8; ++i)
        gl_lds16(s2 + i * 1024, &sbuf[w][ch & 1][i * 1024 + lane * 16]);
    }
  }

  // ---- phase 3: stash per-lane top-2, merge per point, gate + refine ----
  topbuf[tid * 4 + 0] = b1[0];
  topbuf[tid * 4 + 1] = b2[0];
  topbuf[tid * 4 + 2] = b1[1];
  topbuf[tid * 4 + 3] = b2[1];
  __syncthreads();

  if (tid < 128) {  // one thread per point; tid == point-in-block by construction
    const int mw = tid >> 5, mpt = (tid >> 4) & 1, mcol = tid & 15;
    float cv[8];
    int cq[8];
    float mv0 = INF, mv1 = INF;
    int q0 = 0;
#pragma unroll
    for (int q = 0; q < 4; ++q) {
      int lbase = (mw * 64 + q * 16 + mcol) * 4 + mpt * 2;
#pragma unroll
      for (int j = 0; j < 2; ++j) {
        float v = topbuf[lbase + j];
        cv[q * 2 + j] = v;
        cq[q * 2 + j] = q;
        if (v < mv0) { mv1 = mv0; mv0 = v; q0 = q; }
        else if (v < mv1) { mv1 = v; }
      }
    }
    u32 lb = __float_as_uint(mv0) & 255u;
    // id = ch*8 + ct2*4 + r ; k = ch*32 + ct2*16 + quad*4 + r
    int bestk = (int)((lb >> 3) * 32 + ((lb >> 2) & 1) * 16 + q0 * 4 + (lb & 3));

    if (mv1 - mv0 < GATE) {
      // ----- exact emulation of the np reference's fp32 arithmetic -----
      const float* f = x + (size_t)(blockBase + tid) * 64;
      float r8[8];
#pragma unroll
      for (int j = 0; j < 8; ++j) { float fv = f[j]; r8[j] = __fmul_rn(fv, fv); }
#pragma unroll
      for (int i = 8; i < D; i += 8)
#pragma unroll
        for (int j = 0; j < 8; ++j) {
          float fv = f[i + j];
          r8[j] = __fadd_rn(r8[j], __fmul_rn(fv, fv));
        }
      float A = __fadd_rn(__fadd_rn(__fadd_rn(r8[0], r8[1]), __fadd_rn(r8[2], r8[3])),
                          __fadd_rn(__fadd_rn(r8[4], r8[5]), __fadd_rn(r8[6], r8[7])));
      float bd = INF;
      int bkk = K;
#pragma unroll
      for (int c = 0; c < 8; ++c) {
        u32 cb = __float_as_uint(cv[c]) & 255u;
        int k = (int)((cb >> 3) * 32 + ((cb >> 2) & 1) * 16 + cq[c] * 4 + (cb & 3));
        // Et row is d-ascending -> identical fp32 fma sequence, contiguous loads
        const float* er = Etg + (size_t)k * 64;
        float m = 0.f;
#pragma unroll
        for (int d = 0; d < D; ++d) m = __fmaf_rn(f[d], er[d], m);
        float dist = __fadd_rn(__fsub_rn(A, __fmul_rn(2.f, m)), eC[k]);
        bool better = (dist < bd) || (dist == bd && k < bkk);
        bd = better ? dist : bd;
        bkk = better ? k : bkk;
      }
      bestk = bkk;
    }

    bkbuf[tid] = bestk;
    out[QOFF + 2 + blockBase + tid] = (float)bestk;  // index (exact as float)
    atomicAdd(&counts[bestk], 1);
  }
  __syncthreads();

  // ---- phase 4: quantized write (gather from Et, coalesced) + loss ----
  const int pp = tid >> 1, half = tid & 1;
  const int bk = bkbuf[pp];
  const float4* et = (const float4*)(Etg + (size_t)bk * 64 + half * 32);
  const float4* xr = (const float4*)(x + (size_t)(blockBase + pp) * 64 + half * 32);
  float4* ov = (float4*)(out + (size_t)(blockBase + pp) * 64 + half * 32);
  float errs = 0.f;
#pragma unroll
  for (int i = 0; i < 8; ++i) {
    float4 qv = et[i];
    float4 xv = xr[i];
    float dx;
    dx = qv.x - xv.x; errs = fmaf(dx, dx, errs);
    dx = qv.y - xv.y; errs = fmaf(dx, dx, errs);
    dx = qv.z - xv.z; errs = fmaf(dx, dx, errs);
    dx = qv.w - xv.w; errs = fmaf(dx, dx, errs);
    ov[i] = qv;
  }
  double de = (double)errs;
#pragma unroll
  for (int off = 32; off > 0; off >>= 1) de += __shfl_down(de, off, 64);
  if (lane == 0) atomicAdd(lossSum, de);

  // ---- phase 5: ticket finalize, NO threadfence ----
  // __syncthreads drains vmcnt(0) per wave => this block's device-scope
  // atomics (counts/lossSum) are globally performed before the ticket.
  // Last block consumes ONLY atomics-written data (counts/lossSum) via
  // agent-scope atomic loads — no fence / no L2 writeback needed.
  __syncthreads();
  if (tid == 0) {
    int t = __hip_atomic_fetch_add(done, 1, __ATOMIC_RELAXED,
                                   __HIP_MEMORY_SCOPE_AGENT);
    lastFlag = (t == (int)gridDim.x - 1);
  }
  __syncthreads();
  if (lastFlag) {
    double ent = 0.0;
    for (int k = tid; k < K; k += 256) {
      int c = __hip_atomic_load(&counts[k], __ATOMIC_RELAXED,
                                __HIP_MEMORY_SCOPE_AGENT);
      double pp2 = (double)c / (double)NPTS;
      ent += pp2 * log(pp2 + 1e-10);
    }
    double* sh = (double*)topbuf;  // reuse (4KB >= 2KB)
    sh[tid] = ent;
    __syncthreads();
    for (int s = 128; s > 0; s >>= 1) {
      if (tid < s) sh[tid] += sh[tid + s];
      __syncthreads();
    }
    if (tid == 0) {
      unsigned long long lb = __hip_atomic_load((const unsigned long long*)lossSum,
                                                __ATOMIC_RELAXED,
                                                __HIP_MEMORY_SCOPE_AGENT);
      double L = __longlong_as_double(lb);
      // loss = q_latent + 0.25 * e_latent = 1.25 * mean((q - x)^2)
      out[QOFF + 0] = (float)(1.25 * L / (double)((long)NPTS * D));
      out[QOFF + 1] = (float)exp(-sh[0]);  // perplexity
    }
  }
}

extern "C" void kernel_launch(void* const* d_in, const int* in_sizes, int n_in,
                              void* d_out, int out_size, void* d_ws, size_t ws_size,
                              hipStream_t stream) {
  const float* x = (const float*)d_in[0];
  const float* E = (const float*)d_in[1];
  float* out = (float*)d_out;

  char* ws = (char*)d_ws;
  double* lossSum = (double*)(ws + OFF_LOSS);
  int* done = (int*)(ws + OFF_DONE);
  int* counts = (int*)(ws + OFF_CNT);
  float* eC = (float*)(ws + OFF_EC);
  float* eCb = (float*)(ws + OFF_ECB);
  float* Etg = (float*)(ws + OFF_ET);
  unsigned char* stgb = (unsigned char*)(ws + OFF_STG);

  // prep zeroes lossSum/counts/done itself (ws is poisoned before every
  // timed launch); finalize fused into vq_main's last block (2 dispatches).
  vq_prep<<<36, 256, 0, stream>>>(E, eC, eCb, Etg, stgb, lossSum, counts, done);
  vq_main<<<NPTS / 128, 256, 0, stream>>>(x, stgb, eC, eCb, Etg, out,
                                          lossSum, counts, done);
}

// Round 8
// 128.990 us; speedup vs baseline: 1.1201x; 1.0519x over previous
//
#include <hip/hip_runtime.h>
#include <math.h>

// VQ-VAE VectorQuantizer forward (MFMA bf16-split formulation), round N+8.
// R7 post-mortem: bundled two grafts; bank-conflict counter dropped 2.1M->12K
// with NO speed gain (the 2.1M was bit-identical across 4 different layouts
// -> counting artifact, not throughput), while vq_main grew 63->73us. Prime
// suspect: the in-kernel ticket finalize (serialized single-address fetch_add
// round-trips + extra vmcnt-draining barrier + last-block tail).
// This round: R5's proven 3-dispatch structure (separate 1-block finalize,
// NO ticket/done) + fragment-linear staging image (R6/R7-proven, clean
// counters). Exactly one delta vs R5 (the image/read layout) -> this bench
// finishes the attribution either way.

typedef __attribute__((ext_vector_type(8))) short short8v;
typedef __attribute__((ext_vector_type(4))) float float4v;
typedef unsigned short u16;
typedef unsigned int u32;

constexpr int D = 64;
constexpr int K = 1024;
constexpr int NPTS = 65536;
constexpr long QOFF = (long)NPTS * D;  // 4194304
constexpr float BIAS = 24.0f;
constexpr float GATE = 5e-3f;  // 2*(split 5e-4 + pack 1e-3) + ref err 2e-4 + margin

// ws layout (16B-aligned sections):
constexpr size_t OFF_LOSS = 0;                               // double
constexpr size_t OFF_CNT  = 256;                             // int[1024]
constexpr size_t OFF_EC   = OFF_CNT + 4096;                  // float[1024] ref-order norms
constexpr size_t OFF_ECB  = OFF_EC + 4096;                   // float[1024] norms + BIAS
constexpr size_t OFF_ET   = OFF_ECB + 4096;                  // float[1024*64] E transposed [k][d]
constexpr size_t OFF_STG  = OFF_ET + (size_t)K * D * 4;      // 256KB fragment-linear staging image

__device__ __forceinline__ float med3(float a, float b, float c) {
  return __builtin_amdgcn_fmed3f(a, b, c);
}
__device__ __forceinline__ u16 bf16rtn(float x) {
  u32 u = __float_as_uint(x);
  return (u16)((u + 0x7fffu + ((u >> 16) & 1u)) >> 16);
}
__device__ __forceinline__ float bf2f(u16 h) {
  return __uint_as_float(((u32)h) << 16);
}
// async global->LDS, 16B per lane; dest must be wave-uniform base + lane*16.
__device__ __forceinline__ void gl_lds16(const void* g, void* l) {
  __builtin_amdgcn_global_load_lds(
      (const __attribute__((address_space(1))) u32*)g,
      (__attribute__((address_space(3))) u32*)l, 16, 0, 0);
}

// ---------------------------------------------------------------------------
// Prep, grid 36 x 256 (fragment-linear image — proven correct R6/R7):
//   blocks 0..31: Et rows + fragment-linear -2E bf16 hi/lo staging image.
//   blocks 32..35: ref-order ||e_k||^2, eCb, counts/loss zeroing.
// Fragment-linear image: 64 tiles of 16 codes; tile t = k>>4 at byte t*4096;
//   frag f in {0:hi-s0, 1:hi-s1, 2:lo-s0, 3:lo-s1} at f*1024;
//   16B unit for (code k, d-octet q of s-half) at lane (q*16 + (k&15)) * 16.
// Wave ds_read of a frag is lane-linear (conflict-free); staging a whole 8KB
// chunk (2 tiles = 32 codes) is a contiguous 16B-granular copy.
__global__ __launch_bounds__(256) void vq_prep(const float* __restrict__ E,
                                               float* __restrict__ eC,
                                               float* __restrict__ eCb,
                                               float* __restrict__ Et,
                                               unsigned char* __restrict__ stg,
                                               double* __restrict__ lossSum,
                                               int* __restrict__ counts) {
  const int b = blockIdx.x;
  const int tid = threadIdx.x;
  if (b < 32) {
    int gid = b * 256 + tid;
    int k = gid & 1023;        // block covers 256 consecutive k -> coalesced
    int g = gid >> 10;         // d-group 0..7, d = g*8 + j
    float v[8];
#pragma unroll
    for (int j = 0; j < 8; ++j) v[j] = E[(g * 8 + j) * K + k];
    *(float4*)&Et[(size_t)k * 64 + g * 8] = make_float4(v[0], v[1], v[2], v[3]);
    *(float4*)&Et[(size_t)k * 64 + g * 8 + 4] = make_float4(v[4], v[5], v[6], v[7]);
    short8v hv, lv;
#pragma unroll
    for (int j = 0; j < 8; ++j) {
      float m2 = -2.0f * v[j];  // exact
      u16 h = bf16rtn(m2);
      hv[j] = (short)h;
      lv[j] = (short)bf16rtn(m2 - bf2f(h));
    }
    int s = g >> 2, q = g & 3;  // d = s*32 + q*8 + j
    size_t tb = (size_t)(k >> 4) * 4096;
    int lanoff = (q * 16 + (k & 15)) * 16;
    *(short8v*)&stg[tb + (size_t)s * 1024 + lanoff] = hv;        // hi frag
    *(short8v*)&stg[tb + (size_t)(2 + s) * 1024 + lanoff] = lv;  // lo frag
  } else {
    int k = (b - 32) * 256 + tid;  // 0..1023
    float c = __fmul_rn(E[k], E[k]);
#pragma unroll
    for (int d = 1; d < D; ++d) {
      float vv = E[d * K + k];
      c = __fadd_rn(c, __fmul_rn(vv, vv));
    }
    eC[k] = c;
    eCb[k] = c + BIAS;
    counts[k] = 0;
    if (k == 0) *lossSum = 0.0;
  }
}

// ---------------------------------------------------------------------------
// R5 vq_main (measured 63us: wave-private zero-barrier K-loop) with
// fragment-linear lane-linear ds_reads. NO ticket finalize (R7's regression).
__global__ __launch_bounds__(256) void vq_main(const float* __restrict__ x,
                                               const unsigned char* __restrict__ stg,
                                               const float* __restrict__ eC,
                                               const float* __restrict__ eCb,
                                               const float* __restrict__ Etg,
                                               float* __restrict__ out,
                                               double* __restrict__ lossSum,
                                               int* __restrict__ counts) {
  // Wave-private staging: sbuf[wave][buf] 8KB each = 64KB; + ecb 4KB +
  // topbuf 4KB + bkbuf -> ~72.7KB => 2 blocks/CU.
  __shared__ __align__(16) unsigned char sbuf[4][2][8192];
  __shared__ __align__(16) float ecb[1024];
  __shared__ __align__(16) float topbuf[256 * 4];
  __shared__ int bkbuf[128];

  const int tid = threadIdx.x;
  const int w = tid >> 6;        // wave id: owns point-tiles 2w, 2w+1
  const int lane = tid & 63;
  const int col = lane & 15;     // A: code row; B/C: point col
  const int quad = lane >> 4;    // k-group (A/B), row-group (C)
  const int blockBase = blockIdx.x * 128;
  const float INF = __builtin_inff();

  // ---- phase 0: stage all biased norms once (plain LDS copy) ----
  *(float4*)&ecb[tid * 4] = *(const float4*)&eCb[tid * 4];

  // ---- phase 1: load + split x into B-fragments (register-resident) ----
  short8v Bh[2][2], Bl[2][2];
#pragma unroll
  for (int pt = 0; pt < 2; ++pt) {
    const float* xp = x + (size_t)(blockBase + w * 32 + pt * 16 + col) * 64;
#pragma unroll
    for (int s = 0; s < 2; ++s) {
      const float4* src = (const float4*)(xp + s * 32 + quad * 8);
      float4 a = src[0], b = src[1];
      float xs[8] = {a.x, a.y, a.z, a.w, b.x, b.y, b.z, b.w};
      short8v hf, lf;
#pragma unroll
      for (int j = 0; j < 8; ++j) {
        u16 h = bf16rtn(xs[j]);
        hf[j] = (short)h;
        lf[j] = (short)bf16rtn(xs[j] - bf2f(h));
      }
      Bh[pt][s] = hf;
      Bl[pt][s] = lf;
    }
  }

  // ---- prologue: this wave stages mini-chunks 0 and 1 into its own bufs ----
  {
    const unsigned char* s0 = stg + (size_t)lane * 16;
#pragma unroll
    for (int i = 0; i < 8; ++i)
      gl_lds16(s0 + i * 1024, &sbuf[w][0][i * 1024 + lane * 16]);
#pragma unroll
    for (int i = 0; i < 8; ++i)
      gl_lds16(s0 + 8192 + i * 1024, &sbuf[w][1][i * 1024 + lane * 16]);
  }
  // ONE barrier: ecb ds_writes visible to all waves. No vmcnt drain — the
  // 16 staged loads stay in flight (wave-private, paced by vmcnt below).
  asm volatile("s_waitcnt lgkmcnt(0)" ::: "memory");
  __builtin_amdgcn_s_barrier();
  __builtin_amdgcn_sched_barrier(0);
  asm volatile("" ::: "memory");

  // running top-2 of packed biased distances, per point-tile
  float b1[2] = {INF, INF}, b2[2] = {INF, INF};

  // ---- phase 2: K loop, 32 wave-private mini-chunks of 32 codes ----
  // Zero barriers: each wave reads only LDS it staged itself; double-buffer
  // paced by counted vmcnt (issue ch+2, wait ch via vmcnt(8)).
#pragma unroll 1
  for (int ch = 0; ch < 32; ++ch) {
    const unsigned char* bufB = sbuf[w][ch & 1];
    if (ch < 31) {
      asm volatile("s_waitcnt vmcnt(8)" ::: "memory");   // ch landed; ch+1 may fly
    } else {
      asm volatile("s_waitcnt vmcnt(0)" ::: "memory");   // last chunk landed
    }
#pragma unroll
    for (int ct2 = 0; ct2 < 2; ++ct2) {  // 2 code-tiles of 16
      // fragment-linear: lane-linear 16B units, conflict-free ds_read_b128
      const unsigned char* fb = bufB + ct2 * 4096 + lane * 16;
      short8v Ah0 = *(const short8v*)(fb);
      short8v Ah1 = *(const short8v*)(fb + 1024);
      short8v Al0 = *(const short8v*)(fb + 2048);
      short8v Al1 = *(const short8v*)(fb + 3072);
      float4v Ci = *(const float4v*)&ecb[ch * 32 + ct2 * 16 + quad * 4];
#pragma unroll
      for (int pt = 0; pt < 2; ++pt) {
        // split accumulators: two independent 3-deep MFMA chains per pt
        float4v Ca = Ci;
        float4v Cb = {0.f, 0.f, 0.f, 0.f};
        Ca = __builtin_amdgcn_mfma_f32_16x16x32_bf16(Ah0, Bh[pt][0], Ca, 0, 0, 0);
        Cb = __builtin_amdgcn_mfma_f32_16x16x32_bf16(Ah1, Bh[pt][1], Cb, 0, 0, 0);
        Ca = __builtin_amdgcn_mfma_f32_16x16x32_bf16(Al0, Bh[pt][0], Ca, 0, 0, 0);
        Cb = __builtin_amdgcn_mfma_f32_16x16x32_bf16(Al1, Bh[pt][1], Cb, 0, 0, 0);
        Ca = __builtin_amdgcn_mfma_f32_16x16x32_bf16(Ah0, Bl[pt][0], Ca, 0, 0, 0);
        Cb = __builtin_amdgcn_mfma_f32_16x16x32_bf16(Ah1, Bl[pt][1], Cb, 0, 0, 0);
#pragma unroll
        for (int r = 0; r < 4; ++r) {
          float dv = Ca[r] + Cb[r];
          // pack local id (ch:5b | ct2:1b | r:2b) into low 8 mantissa bits;
          // (ch,ct2,r) lexicographic == ascending k for fixed quad => ties
          // still resolve toward lower k.
          u32 u = (__float_as_uint(dv) & 0xffffff00u) |
                  (u32)(ch * 8 + ct2 * 4 + r);
          float v = __uint_as_float(u);
          float pb = b1[pt];
          b1[pt] = fminf(pb, v);
          b2[pt] = med3(pb, b2[pt], v);
        }
      }
    }
    // my ds_reads of bufB delivered (wave-local), then overwrite with ch+2.
    asm volatile("s_waitcnt lgkmcnt(0)" ::: "memory");
    if (ch < 30) {
      const unsigned char* s2 = stg + (size_t)(ch + 2) * 8192 + (size_t)lane * 16;
#pragma unroll
      for (int i = 0; i < 8; ++i)
        gl_lds16(s2 + i * 1024, &sbuf[w][ch & 1][i * 1024 + lane * 16]);
    }
  }

  // ---- phase 3: stash per-lane top-2, merge per point, gate + refine ----
  topbuf[tid * 4 + 0] = b1[0];
  topbuf[tid * 4 + 1] = b2[0];
  topbuf[tid * 4 + 2] = b1[1];
  topbuf[tid * 4 + 3] = b2[1];
  __syncthreads();

  if (tid < 128) {  // one thread per point; tid == point-in-block by construction
    const int mw = tid >> 5, mpt = (tid >> 4) & 1, mcol = tid & 15;
    float cv[8];
    int cq[8];
    float mv0 = INF, mv1 = INF;
    int q0 = 0;
#pragma unroll
    for (int q = 0; q < 4; ++q) {
      int lbase = (mw * 64 + q * 16 + mcol) * 4 + mpt * 2;
#pragma unroll
      for (int j = 0; j < 2; ++j) {
        float v = topbuf[lbase + j];
        cv[q * 2 + j] = v;
        cq[q * 2 + j] = q;
        if (v < mv0) { mv1 = mv0; mv0 = v; q0 = q; }
        else if (v < mv1) { mv1 = v; }
      }
    }
    u32 lb = __float_as_uint(mv0) & 255u;
    // id = ch*8 + ct2*4 + r ; k = ch*32 + ct2*16 + quad*4 + r
    int bestk = (int)((lb >> 3) * 32 + ((lb >> 2) & 1) * 16 + q0 * 4 + (lb & 3));

    if (mv1 - mv0 < GATE) {
      // ----- exact emulation of the np reference's fp32 arithmetic -----
      const float* f = x + (size_t)(blockBase + tid) * 64;
      float r8[8];
#pragma unroll
      for (int j = 0; j < 8; ++j) { float fv = f[j]; r8[j] = __fmul_rn(fv, fv); }
#pragma unroll
      for (int i = 8; i < D; i += 8)
#pragma unroll
        for (int j = 0; j < 8; ++j) {
          float fv = f[i + j];
          r8[j] = __fadd_rn(r8[j], __fmul_rn(fv, fv));
        }
      float A = __fadd_rn(__fadd_rn(__fadd_rn(r8[0], r8[1]), __fadd_rn(r8[2], r8[3])),
                          __fadd_rn(__fadd_rn(r8[4], r8[5]), __fadd_rn(r8[6], r8[7])));
      float bd = INF;
      int bkk = K;
#pragma unroll
      for (int c = 0; c < 8; ++c) {
        u32 cb = __float_as_uint(cv[c]) & 255u;
        int k = (int)((cb >> 3) * 32 + ((cb >> 2) & 1) * 16 + cq[c] * 4 + (cb & 3));
        // Et row is d-ascending -> identical fp32 fma sequence, contiguous loads
        const float* er = Etg + (size_t)k * 64;
        float m = 0.f;
#pragma unroll
        for (int d = 0; d < D; ++d) m = __fmaf_rn(f[d], er[d], m);
        float dist = __fadd_rn(__fsub_rn(A, __fmul_rn(2.f, m)), eC[k]);
        bool better = (dist < bd) || (dist == bd && k < bkk);
        bd = better ? dist : bd;
        bkk = better ? k : bkk;
      }
      bestk = bkk;
    }

    bkbuf[tid] = bestk;
    out[QOFF + 2 + blockBase + tid] = (float)bestk;  // index (exact as float)
    atomicAdd(&counts[bestk], 1);
  }
  __syncthreads();

  // ---- phase 4: quantized write (gather from Et, coalesced) + loss ----
  const int pp = tid >> 1, half = tid & 1;
  const int bk = bkbuf[pp];
  const float4* et = (const float4*)(Etg + (size_t)bk * 64 + half * 32);
  const float4* xr = (const float4*)(x + (size_t)(blockBase + pp) * 64 + half * 32);
  float4* ov = (float4*)(out + (size_t)(blockBase + pp) * 64 + half * 32);
  float errs = 0.f;
#pragma unroll
  for (int i = 0; i < 8; ++i) {
    float4 qv = et[i];
    float4 xv = xr[i];
    float dx;
    dx = qv.x - xv.x; errs = fmaf(dx, dx, errs);
    dx = qv.y - xv.y; errs = fmaf(dx, dx, errs);
    dx = qv.z - xv.z; errs = fmaf(dx, dx, errs);
    dx = qv.w - xv.w; errs = fmaf(dx, dx, errs);
    ov[i] = qv;
  }
  double de = (double)errs;
#pragma unroll
  for (int off = 32; off > 0; off >>= 1) de += __shfl_down(de, off, 64);
  if (lane == 0) atomicAdd(lossSum, de);
}

__global__ __launch_bounds__(256) void vq_finalize(const double* __restrict__ lossSum,
                                                   const int* __restrict__ counts,
                                                   float* __restrict__ out) {
  __shared__ double sh[256];
  double ent = 0.0;
  for (int k = threadIdx.x; k < K; k += 256) {
    double pp = (double)counts[k] / (double)NPTS;
    ent += pp * log(pp + 1e-10);
  }
  sh[threadIdx.x] = ent;
  __syncthreads();
  for (int s = 128; s > 0; s >>= 1) {
    if (threadIdx.x < s) sh[threadIdx.x] += sh[threadIdx.x + s];
    __syncthreads();
  }
  if (threadIdx.x == 0) {
    // loss = q_latent + 0.25 * e_latent = 1.25 * mean((q - x)^2)
    out[QOFF + 0] = (float)(1.25 * (*lossSum) / (double)((long)NPTS * D));
    out[QOFF + 1] = (float)exp(-sh[0]);  // perplexity
  }
}

extern "C" void kernel_launch(void* const* d_in, const int* in_sizes, int n_in,
                              void* d_out, int out_size, void* d_ws, size_t ws_size,
                              hipStream_t stream) {
  const float* x = (const float*)d_in[0];
  const float* E = (const float*)d_in[1];
  float* out = (float*)d_out;

  char* ws = (char*)d_ws;
  double* lossSum = (double*)(ws + OFF_LOSS);
  int* counts = (int*)(ws + OFF_CNT);
  float* eC = (float*)(ws + OFF_EC);
  float* eCb = (float*)(ws + OFF_ECB);
  float* Etg = (float*)(ws + OFF_ET);
  unsigned char* stgb = (unsigned char*)(ws + OFF_STG);

  // prep zeroes lossSum/counts itself (ws is poisoned before every timed
  // launch); no memset dispatch needed.
  vq_prep<<<36, 256, 0, stream>>>(E, eC, eCb, Etg, stgb, lossSum, counts);
  vq_main<<<NPTS / 128, 256, 0, stream>>>(x, stgb, eC, eCb, Etg, out,
                                          lossSum, counts);
  vq_finalize<<<1, 256, 0, stream>>>(lossSum, counts, out);
}